// Round 10
// baseline (254.068 us; speedup 1.0000x reference)
//
#include <hip/hip_runtime.h>
#include <hip/hip_fp16.h>
#include <math.h>

// GCN 2-layer on MI355X. N=100000, E=3200000, F_IN=256, HID=32, F_OUT=64.
// CSR build: radix by 256-node coarse bucket (write-combined reserved runs,
// packed row<<8|col8), then per-bucket counting sort -> per-node CSR + dinv.
// x@W1 via MFMA fp16 (f32 accum). Aggregations are PLANE-SPLIT: features
// 0-15 / 16-31 stored as separate N*16 fp16 planes (3.2 MB each -> fits the
// 4 MB per-XCD L2), each aggregation runs as two passes so the random row
// gathers (32 B) hit L2 instead of thrashing to L3 (~2.3 TB/s random ceiling).
// dinv folded into source: agg(h)[i] = dinv[i]*(sum_{j->i} g[j] + g[i]), g = dinv.h

#define SHIFT1 8
#define S1 256
#define MAXNB1 400

typedef _Float16 half8 __attribute__((ext_vector_type(8)));
typedef float f32x4 __attribute__((ext_vector_type(4)));

__global__ void k_zero(int* p, int n) {
    int i = blockIdx.x * blockDim.x + threadIdx.x;
    if (i < n) p[i] = 0;
}

// coarse bucket counts, int4-vectorized, per-block LDS histogram
__global__ void k_hist1(const int4* __restrict__ cols4, int* __restrict__ bcnt,
                        int e4, int etail, const int* __restrict__ cols, int nb) {
    __shared__ int h[MAXNB1];
    for (int i = threadIdx.x; i < nb; i += blockDim.x) h[i] = 0;
    __syncthreads();
    for (int i = blockIdx.x * blockDim.x + threadIdx.x; i < e4; i += gridDim.x * blockDim.x) {
        int4 c = cols4[i];
        atomicAdd(&h[c.x >> SHIFT1], 1);
        atomicAdd(&h[c.y >> SHIFT1], 1);
        atomicAdd(&h[c.z >> SHIFT1], 1);
        atomicAdd(&h[c.w >> SHIFT1], 1);
    }
    if (blockIdx.x == 0 && threadIdx.x < etail)
        atomicAdd(&h[cols[e4 * 4 + threadIdx.x] >> SHIFT1], 1);
    __syncthreads();
    for (int i = threadIdx.x; i < nb; i += blockDim.x)
        if (h[i]) atomicAdd(&bcnt[i], h[i]);
}

// exclusive scan of nb (<=512) bucket counts
__global__ void k_scan1(const int* __restrict__ bcnt, int* __restrict__ bptr,
                        int* __restrict__ bfill, int nb, int e) {
    __shared__ int sh[512];
    int tid = threadIdx.x;
    int v = (tid < nb) ? bcnt[tid] : 0;
    sh[tid] = v;
    __syncthreads();
    for (int off = 1; off < 512; off <<= 1) {
        int t = (tid >= off) ? sh[tid - off] : 0;
        __syncthreads();
        sh[tid] += t;
        __syncthreads();
    }
    int excl = sh[tid] - v;
    if (tid < nb) { bptr[tid] = excl; bfill[tid] = excl; }
    if (tid == 0) bptr[nb] = e;
}

// bucket the edges, packed (row<<8)|(col&255); per-block reservation
__launch_bounds__(1024)
__global__ void k_scatter1(const int* __restrict__ rows, const int* __restrict__ cols,
                           int* bfill, unsigned* __restrict__ pk, int e, int nb, int chunk) {
    __shared__ int hist[MAXNB1];
    int tid = threadIdx.x;
    for (int i = tid; i < nb; i += blockDim.x) hist[i] = 0;
    __syncthreads();
    int start = blockIdx.x * chunk;
    int end = min(e, start + chunk);
    for (int i = start + tid; i < end; i += blockDim.x)
        atomicAdd(&hist[cols[i] >> SHIFT1], 1);
    __syncthreads();
    for (int i = tid; i < nb; i += blockDim.x) {
        int c = hist[i];
        if (c) hist[i] = atomicAdd(&bfill[i], c);
    }
    __syncthreads();
    for (int i = start + tid; i < end; i += blockDim.x) {
        int r = rows[i], c = cols[i];
        int pos = atomicAdd(&hist[c >> SHIFT1], 1);
        pk[pos] = ((unsigned)r << SHIFT1) | (unsigned)(c & (S1 - 1));
    }
}

// per-bucket counting sort -> erow + per-node CSR ptr + dinv
__launch_bounds__(512)
__global__ void k_fine256(const unsigned* __restrict__ pk, const int* __restrict__ bptr,
                          int* __restrict__ erow, int* __restrict__ ptr,
                          float* __restrict__ dinv, int n, int nb) {
    __shared__ int cnt[S1], sh[S1], fill[S1];
    int tid = threadIdx.x, b = blockIdx.x;
    if (tid < S1) cnt[tid] = 0;
    __syncthreads();
    int s = bptr[b], e = bptr[b + 1];
    for (int t = s + tid; t < e; t += 512)
        atomicAdd(&cnt[pk[t] & (S1 - 1)], 1);
    __syncthreads();
    int v = (tid < S1) ? cnt[tid] : 0;
    if (tid < S1) sh[tid] = v;
    __syncthreads();
    for (int off = 1; off < S1; off <<= 1) {
        int t = (tid >= off && tid < S1) ? sh[tid - off] : 0;
        __syncthreads();
        if (tid < S1) sh[tid] += t;
        __syncthreads();
    }
    if (tid < S1) {
        int base = sh[tid] - v;
        fill[tid] = base;
        int node = (b << SHIFT1) + tid;
        if (node < n) {
            ptr[node] = s + base;
            dinv[node] = rsqrtf((float)(v + 1));
        }
    }
    if (b == nb - 1 && tid == 0) ptr[n] = e;
    __syncthreads();
    for (int t = s + tid; t < e; t += 512) {
        unsigned p = pk[t];
        int pos = atomicAdd(&fill[p & (S1 - 1)], 1);
        erow[s + pos] = (int)(p >> SHIFT1);
    }
}

// g1 planes = fp16( dinv (.) (x @ W1) ) via MFMA: 64 nodes/block, 4 waves.
__launch_bounds__(256)
__global__ void k_xw_mfma(const float4* __restrict__ x4, const float4* __restrict__ W1_4,
                          const float* __restrict__ dinv, _Float16* __restrict__ g1lo,
                          _Float16* __restrict__ g1hi, int n) {
    __shared__ _Float16 xh[64][264];
    __shared__ _Float16 w1t[32][264];
    int tid = threadIdx.x;
    int base = blockIdx.x * 64;
#pragma unroll
    for (int t = 0; t < 16; ++t) {
        int idx = tid + t * 256;
        int row = idx >> 6, c4 = idx & 63;
        float4 v = (base + row < n) ? x4[(size_t)(base + row) * 64 + c4]
                                    : make_float4(0.f, 0.f, 0.f, 0.f);
        __half2 a = __floats2half2_rn(v.x, v.y);
        __half2 b = __floats2half2_rn(v.z, v.w);
        *reinterpret_cast<int2*>(&xh[row][c4 * 4]) = make_int2(*(int*)&a, *(int*)&b);
    }
#pragma unroll
    for (int t = 0; t < 8; ++t) {
        int idx = tid + t * 256;
        int kk = idx >> 3, n4 = idx & 7;
        float4 w = W1_4[idx];
        w1t[n4 * 4 + 0][kk] = (_Float16)w.x;
        w1t[n4 * 4 + 1][kk] = (_Float16)w.y;
        w1t[n4 * 4 + 2][kk] = (_Float16)w.z;
        w1t[n4 * 4 + 3][kk] = (_Float16)w.w;
    }
    __syncthreads();
    int wid = tid >> 6, lane = tid & 63;
    int lrow = lane & 15, kgrp = lane >> 4;
    const _Float16* ap  = &xh[wid * 16 + lrow][kgrp * 8];
    const _Float16* bp0 = &w1t[lrow][kgrp * 8];
    const _Float16* bp1 = &w1t[16 + lrow][kgrp * 8];
    f32x4 acc0 = {0.f, 0.f, 0.f, 0.f}, acc1 = {0.f, 0.f, 0.f, 0.f};
#pragma unroll
    for (int kk = 0; kk < 8; ++kk) {
        half8 a  = *reinterpret_cast<const half8*>(ap + kk * 32);
        half8 b0 = *reinterpret_cast<const half8*>(bp0 + kk * 32);
        half8 b1 = *reinterpret_cast<const half8*>(bp1 + kk * 32);
        acc0 = __builtin_amdgcn_mfma_f32_16x16x32_f16(a, b0, acc0, 0, 0, 0);
        acc1 = __builtin_amdgcn_mfma_f32_16x16x32_f16(a, b1, acc1, 0, 0, 0);
    }
    // C/D: col = lane&15, row = (lane>>4)*4 + reg  [HW-verified]
#pragma unroll
    for (int r = 0; r < 4; ++r) {
        int node = base + wid * 16 + kgrp * 4 + r;
        if (node < n) {
            float d = dinv[node];
            g1lo[(size_t)node * 16 + lrow] = (_Float16)(acc0[r] * d);
            g1hi[(size_t)node * 16 + lrow] = (_Float16)(acc1[r] * d);
        }
    }
}

// accumulate 8 halves (one 16B load) into 8 f32 accumulators
__device__ inline void acc8(float* a, float4 q) {
    const __half2* h = reinterpret_cast<const __half2*>(&q);
#pragma unroll
    for (int i = 0; i < 4; ++i) {
        float2 f = __half22float2(h[i]);
        a[2 * i] += f.x; a[2 * i + 1] += f.y;
    }
}

// shared gather core: 2 lanes/node, 16B/lane, 8-wide unroll over one plane
#define GATHER_PLANE(gsrc)                                                        \
    float a[8] = {0, 0, 0, 0, 0, 0, 0, 0};                                        \
    float b[8] = {0, 0, 0, 0, 0, 0, 0, 0};                                        \
    {                                                                             \
        acc8(a, gsrc[(size_t)node * 2 + l]);                                      \
        int t = s;                                                                \
        for (; t + 7 < e; t += 8) {                                               \
            int r0 = erow[t],     r1 = erow[t + 1], r2 = erow[t + 2], r3 = erow[t + 3]; \
            int r4 = erow[t + 4], r5 = erow[t + 5], r6 = erow[t + 6], r7 = erow[t + 7]; \
            float4 q0 = gsrc[(size_t)r0 * 2 + l];                                 \
            float4 q1 = gsrc[(size_t)r1 * 2 + l];                                 \
            float4 q2 = gsrc[(size_t)r2 * 2 + l];                                 \
            float4 q3 = gsrc[(size_t)r3 * 2 + l];                                 \
            float4 q4 = gsrc[(size_t)r4 * 2 + l];                                 \
            float4 q5 = gsrc[(size_t)r5 * 2 + l];                                 \
            float4 q6 = gsrc[(size_t)r6 * 2 + l];                                 \
            float4 q7 = gsrc[(size_t)r7 * 2 + l];                                 \
            acc8(a, q0); acc8(b, q1); acc8(a, q2); acc8(b, q3);                   \
            acc8(a, q4); acc8(b, q5); acc8(a, q6); acc8(b, q7);                   \
        }                                                                         \
        for (; t < e; ++t) acc8(a, gsrc[(size_t)erow[t] * 2 + l]);                \
    }

// layer-1 aggregate, one 16-feature plane: g2 plane = fp16(dinv.relu(dinv*sum + b1_plane))
__launch_bounds__(256)
__global__ void k_agg1p(const float4* __restrict__ gsrc, const int* __restrict__ erow,
                        const int* __restrict__ ptr, const float* __restrict__ dinv,
                        const float* __restrict__ b1f, int4* __restrict__ gdst, int n) {
    int tid = threadIdx.x;
    int g = tid >> 1, l = tid & 1;
    int node = blockIdx.x * 128 + g;
    if (node >= n) return;
    int s = ptr[node], e = ptr[node + 1];
    GATHER_PLANE(gsrc)
    float d = dinv[node];
    float4 bb0 = *reinterpret_cast<const float4*>(&b1f[l * 8]);
    float4 bb1 = *reinterpret_cast<const float4*>(&b1f[l * 8 + 4]);
    float o[8];
#pragma unroll
    for (int i = 0; i < 8; ++i) {
        float bi = i < 4 ? (&bb0.x)[i] : (&bb1.x)[i - 4];
        float h = fmaf(d, a[i] + b[i], bi);
        o[i] = (h > 0.f ? h : 0.f) * d;
    }
    __half2 h0 = __floats2half2_rn(o[0], o[1]);
    __half2 h1 = __floats2half2_rn(o[2], o[3]);
    __half2 h2 = __floats2half2_rn(o[4], o[5]);
    __half2 h3 = __floats2half2_rn(o[6], o[7]);
    gdst[(size_t)node * 2 + l] = make_int4(*(int*)&h0, *(int*)&h1, *(int*)&h2, *(int*)&h3);
}

// layer-2 aggregate pass A (plane 0): frA[node][0:16] = dinv * sum  (f32)
__launch_bounds__(256)
__global__ void k_agg2a(const float4* __restrict__ gsrc, const int* __restrict__ erow,
                        const int* __restrict__ ptr, const float* __restrict__ dinv,
                        float* __restrict__ frA, int n) {
    int tid = threadIdx.x;
    int g = tid >> 1, l = tid & 1;
    int node = blockIdx.x * 128 + g;
    if (node >= n) return;
    int s = ptr[node], e = ptr[node + 1];
    GATHER_PLANE(gsrc)
    float d = dinv[node];
    float4 o0 = make_float4(d * (a[0] + b[0]), d * (a[1] + b[1]),
                            d * (a[2] + b[2]), d * (a[3] + b[3]));
    float4 o1 = make_float4(d * (a[4] + b[4]), d * (a[5] + b[5]),
                            d * (a[6] + b[6]), d * (a[7] + b[7]));
    *reinterpret_cast<float4*>(&frA[(size_t)node * 16 + l * 8])     = o0;
    *reinterpret_cast<float4*>(&frA[(size_t)node * 16 + l * 8 + 4]) = o1;
}

// layer-2 aggregate pass B (plane 1) + fused W2 projection over all 32 features
__launch_bounds__(256)
__global__ void k_agg2b(const float4* __restrict__ gsrc, const int* __restrict__ erow,
                        const int* __restrict__ ptr, const float* __restrict__ dinv,
                        const float4* __restrict__ frA4, const float* __restrict__ W2,
                        const float* __restrict__ b2, float* __restrict__ out, int n) {
    __shared__ float fr[128][33];
    __shared__ float w2s[32 * 64];
    int tid = threadIdx.x;
    for (int t = tid; t < 32 * 64; t += 256) w2s[t] = W2[t];
    int g = tid >> 1, l = tid & 1;
    int node = blockIdx.x * 128 + g;
    if (node < n) {
        int s = ptr[node], e = ptr[node + 1];
        GATHER_PLANE(gsrc)
        float d = dinv[node];
        float4 fa = frA4[(size_t)node * 4 + l * 2];
        float4 fb = frA4[(size_t)node * 4 + l * 2 + 1];
        *reinterpret_cast<float4*>(&fr[g][l * 8])     = fa;
        *reinterpret_cast<float4*>(&fr[g][l * 8 + 4]) = fb;
#pragma unroll
        for (int i = 0; i < 8; ++i) fr[g][16 + l * 8 + i] = d * (a[i] + b[i]);
    }
    __syncthreads();
    int j = tid & 63, mg = tid >> 6;   // 4 waves x 32 nodes each
    for (int mm = 0; mm < 32; ++mm) {
        int m = mg * 32 + mm;
        int node2 = blockIdx.x * 128 + m;
        if (node2 >= n) continue;
        float sacc = b2[j];
#pragma unroll
        for (int i = 0; i < 32; ++i)
            sacc = fmaf(fr[m][i], w2s[i * 64 + j], sacc);
        out[(size_t)node2 * 64 + j] = sacc;
    }
}

extern "C" void kernel_launch(void* const* d_in, const int* in_sizes, int n_in,
                              void* d_out, int out_size, void* d_ws, size_t ws_size,
                              hipStream_t stream) {
    const float* x  = (const float*)d_in[0];
    const int*   ei = (const int*)d_in[1];
    const float* W1 = (const float*)d_in[2];
    const float* b1 = (const float*)d_in[3];
    const float* W2 = (const float*)d_in[4];
    const float* b2 = (const float*)d_in[5];
    float* out = (float*)d_out;

    const int N = in_sizes[0] / 256;
    const int E = in_sizes[1] / 2;
    const int* rows = ei;        // edge_index[0] (source)
    const int* cols = ei + E;    // edge_index[1] (dest)
    const int NB1 = (N + S1 - 1) >> SHIFT1;   // 391 coarse buckets
    const size_t N16 = (size_t)N * 16;

    // ws layout (4B units):
    // buf0 = pk[E] (CSR build) aliased with g1 planes (2 x N*16 fp16 = N*16 words)
    // | erow[E] | g2 planes (N*16 words) | dinv[N] | ptr[N+1] | bptr1 | bcnt1 | bfill1 | frA[N*16]
    size_t sz0 = (size_t)E > N16 ? (size_t)E : N16;
    unsigned* pk   = (unsigned*)d_ws;
    _Float16* g1p  = (_Float16*)d_ws;            // plane p at g1p + p*N16
    int*      erow = (int*)((char*)d_ws + sz0 * 4);
    _Float16* g2p  = (_Float16*)(erow + E);      // plane p at g2p + p*N16
    float*    dinv = (float*)((char*)(erow + E) + (size_t)N * 32 * 2);
    int*      ptr  = (int*)(dinv + N);
    int*      bptr1 = ptr + (N + 1);
    int*      bcnt1 = bptr1 + (NB1 + 1);
    int*      bfill1 = bcnt1 + NB1;
    float*    frA  = (float*)(bfill1 + NB1);

    const int B = 256;
    const int e4 = E / 4, etail = E - e4 * 4;
    const int SCB = 256;
    const int chunk = (E + SCB - 1) / SCB;
    const int nblk64 = (N + 63) / 64;
    const int nblk128 = (N + 127) / 128;

    k_zero<<<(NB1 + B - 1) / B, B, 0, stream>>>(bcnt1, NB1);
    k_hist1<<<256, B, 0, stream>>>((const int4*)cols, bcnt1, e4, etail, cols, NB1);
    k_scan1<<<1, 512, 0, stream>>>(bcnt1, bptr1, bfill1, NB1, E);
    k_scatter1<<<SCB, 1024, 0, stream>>>(rows, cols, bfill1, pk, E, NB1, chunk);
    k_fine256<<<NB1, 512, 0, stream>>>(pk, bptr1, erow, ptr, dinv, N, NB1);
    k_xw_mfma<<<nblk64, B, 0, stream>>>((const float4*)x, (const float4*)W1, dinv,
                                        g1p, g1p + N16, N);
    // layer-1 aggregate: plane 0 then plane 1 (each table 3.2 MB -> L2-resident)
    k_agg1p<<<nblk128, B, 0, stream>>>((const float4*)g1p, erow, ptr, dinv,
                                       b1, (int4*)g2p, N);
    k_agg1p<<<nblk128, B, 0, stream>>>((const float4*)(g1p + N16), erow, ptr, dinv,
                                       b1 + 16, (int4*)(g2p + N16), N);
    // layer-2 aggregate: pass A (plane 0 -> frA), pass B (plane 1 + projection)
    k_agg2a<<<nblk128, B, 0, stream>>>((const float4*)g2p, erow, ptr, dinv, frA, N);
    k_agg2b<<<nblk128, B, 0, stream>>>((const float4*)(g2p + N16), erow, ptr, dinv,
                                       (const float4*)frA, W2, b2, out, N);
}

// Round 11
// 187.841 us; speedup vs baseline: 1.3526x; 1.3526x over previous
//
#include <hip/hip_runtime.h>
#include <hip/hip_fp16.h>
#include <math.h>

// GCN 2-layer on MI355X. N=100000, E=3200000, F_IN=256, HID=32, F_OUT=64.
// CSR build: radix by 256-node coarse bucket (write-combined reserved runs,
// packed row<<8|col8), then per-bucket counting sort -> per-node CSR + dinv.
// x@W1 via MFMA fp16 (f32 accum). Aggregations gather fp16 rows (64B, 4
// lanes/node, 8-wide unroll, f32 accum). Layer-2's W2 projection runs on
// MFMA (fr and W2^T staged fp16 in LDS) instead of the VALU.
// dinv folded into source: agg(h)[i] = dinv[i]*(sum_{j->i} g[j] + g[i]), g = dinv.h

#define SHIFT1 8
#define S1 256
#define MAXNB1 400

typedef _Float16 half8 __attribute__((ext_vector_type(8)));
typedef float f32x4 __attribute__((ext_vector_type(4)));

__global__ void k_zero(int* p, int n) {
    int i = blockIdx.x * blockDim.x + threadIdx.x;
    if (i < n) p[i] = 0;
}

// coarse bucket counts, int4-vectorized, per-block LDS histogram
__global__ void k_hist1(const int4* __restrict__ cols4, int* __restrict__ bcnt,
                        int e4, int etail, const int* __restrict__ cols, int nb) {
    __shared__ int h[MAXNB1];
    for (int i = threadIdx.x; i < nb; i += blockDim.x) h[i] = 0;
    __syncthreads();
    for (int i = blockIdx.x * blockDim.x + threadIdx.x; i < e4; i += gridDim.x * blockDim.x) {
        int4 c = cols4[i];
        atomicAdd(&h[c.x >> SHIFT1], 1);
        atomicAdd(&h[c.y >> SHIFT1], 1);
        atomicAdd(&h[c.z >> SHIFT1], 1);
        atomicAdd(&h[c.w >> SHIFT1], 1);
    }
    if (blockIdx.x == 0 && threadIdx.x < etail)
        atomicAdd(&h[cols[e4 * 4 + threadIdx.x] >> SHIFT1], 1);
    __syncthreads();
    for (int i = threadIdx.x; i < nb; i += blockDim.x)
        if (h[i]) atomicAdd(&bcnt[i], h[i]);
}

// exclusive scan of nb (<=512) bucket counts
__global__ void k_scan1(const int* __restrict__ bcnt, int* __restrict__ bptr,
                        int* __restrict__ bfill, int nb, int e) {
    __shared__ int sh[512];
    int tid = threadIdx.x;
    int v = (tid < nb) ? bcnt[tid] : 0;
    sh[tid] = v;
    __syncthreads();
    for (int off = 1; off < 512; off <<= 1) {
        int t = (tid >= off) ? sh[tid - off] : 0;
        __syncthreads();
        sh[tid] += t;
        __syncthreads();
    }
    int excl = sh[tid] - v;
    if (tid < nb) { bptr[tid] = excl; bfill[tid] = excl; }
    if (tid == 0) bptr[nb] = e;
}

// bucket the edges, packed (row<<8)|(col&255); per-block reservation
__launch_bounds__(1024)
__global__ void k_scatter1(const int* __restrict__ rows, const int* __restrict__ cols,
                           int* bfill, unsigned* __restrict__ pk, int e, int nb, int chunk) {
    __shared__ int hist[MAXNB1];
    int tid = threadIdx.x;
    for (int i = tid; i < nb; i += blockDim.x) hist[i] = 0;
    __syncthreads();
    int start = blockIdx.x * chunk;
    int end = min(e, start + chunk);
    for (int i = start + tid; i < end; i += blockDim.x)
        atomicAdd(&hist[cols[i] >> SHIFT1], 1);
    __syncthreads();
    for (int i = tid; i < nb; i += blockDim.x) {
        int c = hist[i];
        if (c) hist[i] = atomicAdd(&bfill[i], c);
    }
    __syncthreads();
    for (int i = start + tid; i < end; i += blockDim.x) {
        int r = rows[i], c = cols[i];
        int pos = atomicAdd(&hist[c >> SHIFT1], 1);
        pk[pos] = ((unsigned)r << SHIFT1) | (unsigned)(c & (S1 - 1));
    }
}

// per-bucket counting sort -> erow + per-node CSR ptr + dinv
__launch_bounds__(512)
__global__ void k_fine256(const unsigned* __restrict__ pk, const int* __restrict__ bptr,
                          int* __restrict__ erow, int* __restrict__ ptr,
                          float* __restrict__ dinv, int n, int nb) {
    __shared__ int cnt[S1], sh[S1], fill[S1];
    int tid = threadIdx.x, b = blockIdx.x;
    if (tid < S1) cnt[tid] = 0;
    __syncthreads();
    int s = bptr[b], e = bptr[b + 1];
    for (int t = s + tid; t < e; t += 512)
        atomicAdd(&cnt[pk[t] & (S1 - 1)], 1);
    __syncthreads();
    int v = (tid < S1) ? cnt[tid] : 0;
    if (tid < S1) sh[tid] = v;
    __syncthreads();
    for (int off = 1; off < S1; off <<= 1) {
        int t = (tid >= off && tid < S1) ? sh[tid - off] : 0;
        __syncthreads();
        if (tid < S1) sh[tid] += t;
        __syncthreads();
    }
    if (tid < S1) {
        int base = sh[tid] - v;
        fill[tid] = base;
        int node = (b << SHIFT1) + tid;
        if (node < n) {
            ptr[node] = s + base;
            dinv[node] = rsqrtf((float)(v + 1));
        }
    }
    if (b == nb - 1 && tid == 0) ptr[n] = e;
    __syncthreads();
    for (int t = s + tid; t < e; t += 512) {
        unsigned p = pk[t];
        int pos = atomicAdd(&fill[p & (S1 - 1)], 1);
        erow[s + pos] = (int)(p >> SHIFT1);
    }
}

// g1h = fp16( dinv (.) (x @ W1) ) via MFMA: 64 nodes/block, 4 waves.
__launch_bounds__(256)
__global__ void k_xw_mfma(const float4* __restrict__ x4, const float4* __restrict__ W1_4,
                          const float* __restrict__ dinv, _Float16* __restrict__ g1h, int n) {
    __shared__ _Float16 xh[64][264];
    __shared__ _Float16 w1t[32][264];
    int tid = threadIdx.x;
    int base = blockIdx.x * 64;
#pragma unroll
    for (int t = 0; t < 16; ++t) {
        int idx = tid + t * 256;
        int row = idx >> 6, c4 = idx & 63;
        float4 v = (base + row < n) ? x4[(size_t)(base + row) * 64 + c4]
                                    : make_float4(0.f, 0.f, 0.f, 0.f);
        __half2 a = __floats2half2_rn(v.x, v.y);
        __half2 b = __floats2half2_rn(v.z, v.w);
        *reinterpret_cast<int2*>(&xh[row][c4 * 4]) = make_int2(*(int*)&a, *(int*)&b);
    }
#pragma unroll
    for (int t = 0; t < 8; ++t) {
        int idx = tid + t * 256;
        int kk = idx >> 3, n4 = idx & 7;
        float4 w = W1_4[idx];
        w1t[n4 * 4 + 0][kk] = (_Float16)w.x;
        w1t[n4 * 4 + 1][kk] = (_Float16)w.y;
        w1t[n4 * 4 + 2][kk] = (_Float16)w.z;
        w1t[n4 * 4 + 3][kk] = (_Float16)w.w;
    }
    __syncthreads();
    int wid = tid >> 6, lane = tid & 63;
    int lrow = lane & 15, kgrp = lane >> 4;
    const _Float16* ap  = &xh[wid * 16 + lrow][kgrp * 8];
    const _Float16* bp0 = &w1t[lrow][kgrp * 8];
    const _Float16* bp1 = &w1t[16 + lrow][kgrp * 8];
    f32x4 acc0 = {0.f, 0.f, 0.f, 0.f}, acc1 = {0.f, 0.f, 0.f, 0.f};
#pragma unroll
    for (int kk = 0; kk < 8; ++kk) {
        half8 a  = *reinterpret_cast<const half8*>(ap + kk * 32);
        half8 b0 = *reinterpret_cast<const half8*>(bp0 + kk * 32);
        half8 b1 = *reinterpret_cast<const half8*>(bp1 + kk * 32);
        acc0 = __builtin_amdgcn_mfma_f32_16x16x32_f16(a, b0, acc0, 0, 0, 0);
        acc1 = __builtin_amdgcn_mfma_f32_16x16x32_f16(a, b1, acc1, 0, 0, 0);
    }
    // C/D: col = lane&15, row = (lane>>4)*4 + reg  [HW-verified]
#pragma unroll
    for (int r = 0; r < 4; ++r) {
        int node = base + wid * 16 + kgrp * 4 + r;
        if (node < n) {
            float d = dinv[node];
            g1h[(size_t)node * 32 + lrow]      = (_Float16)(acc0[r] * d);
            g1h[(size_t)node * 32 + 16 + lrow] = (_Float16)(acc1[r] * d);
        }
    }
}

// accumulate 8 halves (one 16B load) into 8 f32 accumulators
__device__ inline void acc8(float* a, float4 q) {
    const __half2* h = reinterpret_cast<const __half2*>(&q);
#pragma unroll
    for (int i = 0; i < 4; ++i) {
        float2 f = __half22float2(h[i]);
        a[2 * i] += f.x; a[2 * i + 1] += f.y;
    }
}

// layer-1 aggregate (fp16 CSR gather, 4 lanes/node, 8-wide unroll):
// g2h = fp16( dinv (.) relu(dinv*(sum)+b1) )
__launch_bounds__(256)
__global__ void k_agg1(const float4* __restrict__ g1h4, const int* __restrict__ erow,
                       const int* __restrict__ ptr, const float* __restrict__ dinv,
                       const float* __restrict__ b1, int4* __restrict__ g2h4, int n) {
    int tid = threadIdx.x;
    int g = tid >> 2, l = tid & 3;
    int node = blockIdx.x * 64 + g;
    if (node >= n) return;
    int s = ptr[node], e = ptr[node + 1];
    float a[8] = {0, 0, 0, 0, 0, 0, 0, 0};
    float b[8] = {0, 0, 0, 0, 0, 0, 0, 0};
    acc8(a, g1h4[(size_t)node * 4 + l]);   // self-loop
    int t = s;
    for (; t + 7 < e; t += 8) {
        int r0 = erow[t],     r1 = erow[t + 1], r2 = erow[t + 2], r3 = erow[t + 3];
        int r4 = erow[t + 4], r5 = erow[t + 5], r6 = erow[t + 6], r7 = erow[t + 7];
        float4 q0 = g1h4[(size_t)r0 * 4 + l];
        float4 q1 = g1h4[(size_t)r1 * 4 + l];
        float4 q2 = g1h4[(size_t)r2 * 4 + l];
        float4 q3 = g1h4[(size_t)r3 * 4 + l];
        float4 q4 = g1h4[(size_t)r4 * 4 + l];
        float4 q5 = g1h4[(size_t)r5 * 4 + l];
        float4 q6 = g1h4[(size_t)r6 * 4 + l];
        float4 q7 = g1h4[(size_t)r7 * 4 + l];
        acc8(a, q0); acc8(b, q1); acc8(a, q2); acc8(b, q3);
        acc8(a, q4); acc8(b, q5); acc8(a, q6); acc8(b, q7);
    }
    for (; t < e; ++t) acc8(a, g1h4[(size_t)erow[t] * 4 + l]);
    float d = dinv[node];
    float4 bb0 = *reinterpret_cast<const float4*>(&b1[l * 8]);
    float4 bb1 = *reinterpret_cast<const float4*>(&b1[l * 8 + 4]);
    float o[8];
#pragma unroll
    for (int i = 0; i < 8; ++i) {
        float bi = i < 4 ? (&bb0.x)[i] : (&bb1.x)[i - 4];
        float h = fmaf(d, a[i] + b[i], bi);
        o[i] = (h > 0.f ? h : 0.f) * d;
    }
    __half2 h0 = __floats2half2_rn(o[0], o[1]);
    __half2 h1 = __floats2half2_rn(o[2], o[3]);
    __half2 h2 = __floats2half2_rn(o[4], o[5]);
    __half2 h3 = __floats2half2_rn(o[6], o[7]);
    g2h4[(size_t)node * 4 + l] = make_int4(*(int*)&h0, *(int*)&h1, *(int*)&h2, *(int*)&h3);
}

// layer-2 aggregate (fp16 gather) + W2 projection on MFMA.
// Block: 256 thr = 4 waves, 64 nodes (4 lanes/node). After the gather, the
// 64x32 fr tile is written fp16 to LDS and each wave does a 16x64x32 slab
// with 4x mfma_f32_16x16x32_f16 (frh rows = A, w2h = W2^T as B).
__launch_bounds__(256)
__global__ void k_agg2(const float4* __restrict__ g2h4, const int* __restrict__ erow,
                       const int* __restrict__ ptr, const float* __restrict__ dinv,
                       const float* __restrict__ W2, const float* __restrict__ b2,
                       float* __restrict__ out, int n) {
    __shared__ _Float16 frh[64][40];   // 5.0 KB, row = 80 B (16B-aligned, 2-way banks)
    __shared__ _Float16 w2h[64][40];   // w2h[col][k] = W2[k][col]
    int tid = threadIdx.x;
    {
        int c = tid >> 2, kb = (tid & 3) * 8;
#pragma unroll
        for (int i = 0; i < 8; ++i)
            w2h[c][kb + i] = (_Float16)W2[(kb + i) * 64 + c];
    }
    int g = tid >> 2, l = tid & 3;
    int node = blockIdx.x * 64 + g;
    float a[8] = {0, 0, 0, 0, 0, 0, 0, 0};
    float b[8] = {0, 0, 0, 0, 0, 0, 0, 0};
    float d = 0.f;
    if (node < n) {
        int s = ptr[node], e = ptr[node + 1];
        acc8(a, g2h4[(size_t)node * 4 + l]);   // self-loop
        int t = s;
        for (; t + 7 < e; t += 8) {
            int r0 = erow[t],     r1 = erow[t + 1], r2 = erow[t + 2], r3 = erow[t + 3];
            int r4 = erow[t + 4], r5 = erow[t + 5], r6 = erow[t + 6], r7 = erow[t + 7];
            float4 q0 = g2h4[(size_t)r0 * 4 + l];
            float4 q1 = g2h4[(size_t)r1 * 4 + l];
            float4 q2 = g2h4[(size_t)r2 * 4 + l];
            float4 q3 = g2h4[(size_t)r3 * 4 + l];
            float4 q4 = g2h4[(size_t)r4 * 4 + l];
            float4 q5 = g2h4[(size_t)r5 * 4 + l];
            float4 q6 = g2h4[(size_t)r6 * 4 + l];
            float4 q7 = g2h4[(size_t)r7 * 4 + l];
            acc8(a, q0); acc8(b, q1); acc8(a, q2); acc8(b, q3);
            acc8(a, q4); acc8(b, q5); acc8(a, q6); acc8(b, q7);
        }
        for (; t < e; ++t) acc8(a, g2h4[(size_t)erow[t] * 4 + l]);
        d = dinv[node];
    }
    {
        _Float16 tmp[8];
#pragma unroll
        for (int i = 0; i < 8; ++i) tmp[i] = (_Float16)(d * (a[i] + b[i]));
        *reinterpret_cast<half8*>(&frh[g][l * 8]) = *reinterpret_cast<half8*>(tmp);
    }
    __syncthreads();
    int w = tid >> 6, lane = tid & 63;
    int lcol = lane & 15, kgrp = lane >> 4;
    half8 afrag = *reinterpret_cast<const half8*>(&frh[w * 16 + lcol][kgrp * 8]);
    half8 bf0 = *reinterpret_cast<const half8*>(&w2h[lcol][kgrp * 8]);
    half8 bf1 = *reinterpret_cast<const half8*>(&w2h[16 + lcol][kgrp * 8]);
    half8 bf2 = *reinterpret_cast<const half8*>(&w2h[32 + lcol][kgrp * 8]);
    half8 bf3 = *reinterpret_cast<const half8*>(&w2h[48 + lcol][kgrp * 8]);
    f32x4 c0 = {0.f, 0.f, 0.f, 0.f}, c1 = c0, c2 = c0, c3 = c0;
    c0 = __builtin_amdgcn_mfma_f32_16x16x32_f16(afrag, bf0, c0, 0, 0, 0);
    c1 = __builtin_amdgcn_mfma_f32_16x16x32_f16(afrag, bf1, c1, 0, 0, 0);
    c2 = __builtin_amdgcn_mfma_f32_16x16x32_f16(afrag, bf2, c2, 0, 0, 0);
    c3 = __builtin_amdgcn_mfma_f32_16x16x32_f16(afrag, bf3, c3, 0, 0, 0);
    // C/D: col = lane&15 (output col within tile), row = kgrp*4 + r (node row)
    float bi0 = b2[lcol], bi1 = b2[16 + lcol], bi2 = b2[32 + lcol], bi3 = b2[48 + lcol];
#pragma unroll
    for (int r = 0; r < 4; ++r) {
        int node2 = blockIdx.x * 64 + w * 16 + kgrp * 4 + r;
        if (node2 < n) {
            float* op = &out[(size_t)node2 * 64];
            op[lcol]      = c0[r] + bi0;
            op[16 + lcol] = c1[r] + bi1;
            op[32 + lcol] = c2[r] + bi2;
            op[48 + lcol] = c3[r] + bi3;
        }
    }
}

extern "C" void kernel_launch(void* const* d_in, const int* in_sizes, int n_in,
                              void* d_out, int out_size, void* d_ws, size_t ws_size,
                              hipStream_t stream) {
    const float* x  = (const float*)d_in[0];
    const int*   ei = (const int*)d_in[1];
    const float* W1 = (const float*)d_in[2];
    const float* b1 = (const float*)d_in[3];
    const float* W2 = (const float*)d_in[4];
    const float* b2 = (const float*)d_in[5];
    float* out = (float*)d_out;

    const int N = in_sizes[0] / 256;
    const int E = in_sizes[1] / 2;
    const int* rows = ei;        // edge_index[0] (source)
    const int* cols = ei + E;    // edge_index[1] (dest)
    const int NB1 = (N + S1 - 1) >> SHIFT1;   // 391 coarse buckets

    // ws layout (4B units):
    // buf0 = pk[E] (CSR build) aliased with g1h[N*32 halves] (dead pk after fine)
    // | erow[E] | g2h[N*32 halves] | dinv[N] | ptr[N+1] | bptr1 | bcnt1 | bfill1
    size_t sz0 = (size_t)E > (size_t)N * 16 ? (size_t)E : (size_t)N * 16;
    unsigned* pk  = (unsigned*)d_ws;
    _Float16* g1h = (_Float16*)d_ws;
    int*      erow = (int*)((char*)d_ws + sz0 * 4);
    _Float16* g2h  = (_Float16*)(erow + E);
    float*    dinv = (float*)((char*)(erow + E) + (size_t)N * 32 * 2);
    int*      ptr  = (int*)(dinv + N);
    int*      bptr1 = ptr + (N + 1);
    int*      bcnt1 = bptr1 + (NB1 + 1);
    int*      bfill1 = bcnt1 + NB1;

    const int B = 256;
    const int e4 = E / 4, etail = E - e4 * 4;
    const int SCB = 256;
    const int chunk = (E + SCB - 1) / SCB;
    const int nblk64 = (N + 63) / 64;

    k_zero<<<(NB1 + B - 1) / B, B, 0, stream>>>(bcnt1, NB1);
    k_hist1<<<256, B, 0, stream>>>((const int4*)cols, bcnt1, e4, etail, cols, NB1);
    k_scan1<<<1, 512, 0, stream>>>(bcnt1, bptr1, bfill1, NB1, E);
    k_scatter1<<<SCB, 1024, 0, stream>>>(rows, cols, bfill1, pk, E, NB1, chunk);
    k_fine256<<<NB1, 512, 0, stream>>>(pk, bptr1, erow, ptr, dinv, N, NB1);
    k_xw_mfma<<<nblk64, B, 0, stream>>>((const float4*)x, (const float4*)W1, dinv, g1h, N);
    k_agg1<<<nblk64, B, 0, stream>>>((const float4*)g1h, erow, ptr, dinv, b1, (int4*)g2h, N);
    k_agg2<<<nblk64, B, 0, stream>>>((const float4*)g2h, erow, ptr, dinv, W2, b2, out, N);
}

// Round 12
// 187.080 us; speedup vs baseline: 1.3581x; 1.0041x over previous
//
#include <hip/hip_runtime.h>
#include <hip/hip_fp16.h>
#include <math.h>

// GCN 2-layer on MI355X. N=100000, E=3200000, F_IN=256, HID=32, F_OUT=64.
// CSR build: radix by 256-node coarse bucket, per-bucket counting sort ->
// per-node CSR padded to multiples of 8 edges (sentinel source N = zero row),
// ptr2 = (start, padded_end). Aggregations gather fp16 rows (64B, 4 lanes/
// node); edge ids loaded as one int2 per lane + __shfl distribution (cuts
// TA distinct-line probes ~2x vs per-lane scalar id loads - the measured
// bottleneck). x@W1 and the W2 projection run on MFMA fp16 (f32 accum).
// dinv folded into source: agg(h)[i] = dinv[i]*(sum_{j->i} g[j] + g[i]), g = dinv.h

#define SHIFT1 8
#define S1 256
#define MAXNB1 400
#define BSLACK 2048   // per-bucket erow slack: 256 nodes * 7 max pad + align

typedef _Float16 half8 __attribute__((ext_vector_type(8)));
typedef float f32x4 __attribute__((ext_vector_type(4)));

__global__ void k_zero(int* p, int n) {
    int i = blockIdx.x * blockDim.x + threadIdx.x;
    if (i < n) p[i] = 0;
}

// zero the sentinel row N of both fp16 feature tables
__global__ void k_zrow(_Float16* g1h, _Float16* g2h, int n) {
    int i = threadIdx.x;
    if (i < 16)      ((int*)(g1h + (size_t)n * 32))[i] = 0;
    else if (i < 32) ((int*)(g2h + (size_t)n * 32))[i - 16] = 0;
}

// coarse bucket counts, int4-vectorized, per-block LDS histogram
__global__ void k_hist1(const int4* __restrict__ cols4, int* __restrict__ bcnt,
                        int e4, int etail, const int* __restrict__ cols, int nb) {
    __shared__ int h[MAXNB1];
    for (int i = threadIdx.x; i < nb; i += blockDim.x) h[i] = 0;
    __syncthreads();
    for (int i = blockIdx.x * blockDim.x + threadIdx.x; i < e4; i += gridDim.x * blockDim.x) {
        int4 c = cols4[i];
        atomicAdd(&h[c.x >> SHIFT1], 1);
        atomicAdd(&h[c.y >> SHIFT1], 1);
        atomicAdd(&h[c.z >> SHIFT1], 1);
        atomicAdd(&h[c.w >> SHIFT1], 1);
    }
    if (blockIdx.x == 0 && threadIdx.x < etail)
        atomicAdd(&h[cols[e4 * 4 + threadIdx.x] >> SHIFT1], 1);
    __syncthreads();
    for (int i = threadIdx.x; i < nb; i += blockDim.x)
        if (h[i]) atomicAdd(&bcnt[i], h[i]);
}

// exclusive scan of nb (<=512) bucket counts
__global__ void k_scan1(const int* __restrict__ bcnt, int* __restrict__ bptr,
                        int* __restrict__ bfill, int nb, int e) {
    __shared__ int sh[512];
    int tid = threadIdx.x;
    int v = (tid < nb) ? bcnt[tid] : 0;
    sh[tid] = v;
    __syncthreads();
    for (int off = 1; off < 512; off <<= 1) {
        int t = (tid >= off) ? sh[tid - off] : 0;
        __syncthreads();
        sh[tid] += t;
        __syncthreads();
    }
    int excl = sh[tid] - v;
    if (tid < nb) { bptr[tid] = excl; bfill[tid] = excl; }
    if (tid == 0) bptr[nb] = e;
}

// bucket the edges, packed (row<<8)|(col&255); per-block reservation
__launch_bounds__(1024)
__global__ void k_scatter1(const int* __restrict__ rows, const int* __restrict__ cols,
                           int* bfill, unsigned* __restrict__ pk, int e, int nb, int chunk) {
    __shared__ int hist[MAXNB1];
    int tid = threadIdx.x;
    for (int i = tid; i < nb; i += blockDim.x) hist[i] = 0;
    __syncthreads();
    int start = blockIdx.x * chunk;
    int end = min(e, start + chunk);
    for (int i = start + tid; i < end; i += blockDim.x)
        atomicAdd(&hist[cols[i] >> SHIFT1], 1);
    __syncthreads();
    for (int i = tid; i < nb; i += blockDim.x) {
        int c = hist[i];
        if (c) hist[i] = atomicAdd(&bfill[i], c);
    }
    __syncthreads();
    for (int i = start + tid; i < end; i += blockDim.x) {
        int r = rows[i], c = cols[i];
        int pos = atomicAdd(&hist[c >> SHIFT1], 1);
        pk[pos] = ((unsigned)r << SHIFT1) | (unsigned)(c & (S1 - 1));
    }
}

// per-bucket counting sort -> padded per-node CSR (erow in its own padded
// address space; each node's region 8-aligned, length multiple of 8,
// pad slots = sentinel n). Emits ptr2=(start,end_pad) + dinv.
__launch_bounds__(512)
__global__ void k_fine256(const unsigned* __restrict__ pk, const int* __restrict__ bptr,
                          int* __restrict__ erow, int2* __restrict__ ptr2,
                          float* __restrict__ dinv, int n, int nb) {
    __shared__ int cnt[S1], sh[S1], fill[S1], pvs[S1];
    int tid = threadIdx.x, b = blockIdx.x;
    if (tid < S1) cnt[tid] = 0;
    __syncthreads();
    int s = bptr[b], e = bptr[b + 1];
    for (int t = s + tid; t < e; t += 512)
        atomicAdd(&cnt[pk[t] & (S1 - 1)], 1);
    __syncthreads();
    int v = 0, pv = 0;
    if (tid < S1) {
        v = cnt[tid];
        pv = (v + 7) & ~7;
        sh[tid] = pv;
        pvs[tid] = pv;
    }
    __syncthreads();
    for (int off = 1; off < S1; off <<= 1) {
        int t = (tid >= off && tid < S1) ? sh[tid - off] : 0;
        __syncthreads();
        if (tid < S1) sh[tid] += t;
        __syncthreads();
    }
    int mybase = 0;
    if (tid < S1) {
        int base = sh[tid] - pv;
        int ebase = ((s + b * BSLACK) + 7) & ~7;
        mybase = ebase + base;
        fill[tid] = mybase;
        int node = (b << SHIFT1) + tid;
        if (node < n) {
            ptr2[node] = make_int2(mybase, mybase + pv);
            dinv[node] = rsqrtf((float)(v + 1));
        }
    }
    __syncthreads();
    for (int t = s + tid; t < e; t += 512) {
        unsigned p = pk[t];
        int pos = atomicAdd(&fill[p & (S1 - 1)], 1);
        erow[pos] = (int)(p >> SHIFT1);
    }
    __syncthreads();
    if (tid < S1) {
        int endv = mybase + v;          // == fill[tid] after scatter
        int endp = mybase + pvs[tid];
        for (int i = endv; i < endp; ++i) erow[i] = n;   // sentinel pads
    }
}

// g1h = fp16( dinv (.) (x @ W1) ) via MFMA: 64 nodes/block, 4 waves.
__launch_bounds__(256)
__global__ void k_xw_mfma(const float4* __restrict__ x4, const float4* __restrict__ W1_4,
                          const float* __restrict__ dinv, _Float16* __restrict__ g1h, int n) {
    __shared__ _Float16 xh[64][264];
    __shared__ _Float16 w1t[32][264];
    int tid = threadIdx.x;
    int base = blockIdx.x * 64;
#pragma unroll
    for (int t = 0; t < 16; ++t) {
        int idx = tid + t * 256;
        int row = idx >> 6, c4 = idx & 63;
        float4 v = (base + row < n) ? x4[(size_t)(base + row) * 64 + c4]
                                    : make_float4(0.f, 0.f, 0.f, 0.f);
        __half2 a = __floats2half2_rn(v.x, v.y);
        __half2 b = __floats2half2_rn(v.z, v.w);
        *reinterpret_cast<int2*>(&xh[row][c4 * 4]) = make_int2(*(int*)&a, *(int*)&b);
    }
#pragma unroll
    for (int t = 0; t < 8; ++t) {
        int idx = tid + t * 256;
        int kk = idx >> 3, n4 = idx & 7;
        float4 w = W1_4[idx];
        w1t[n4 * 4 + 0][kk] = (_Float16)w.x;
        w1t[n4 * 4 + 1][kk] = (_Float16)w.y;
        w1t[n4 * 4 + 2][kk] = (_Float16)w.z;
        w1t[n4 * 4 + 3][kk] = (_Float16)w.w;
    }
    __syncthreads();
    int wid = tid >> 6, lane = tid & 63;
    int lrow = lane & 15, kgrp = lane >> 4;
    const _Float16* ap  = &xh[wid * 16 + lrow][kgrp * 8];
    const _Float16* bp0 = &w1t[lrow][kgrp * 8];
    const _Float16* bp1 = &w1t[16 + lrow][kgrp * 8];
    f32x4 acc0 = {0.f, 0.f, 0.f, 0.f}, acc1 = {0.f, 0.f, 0.f, 0.f};
#pragma unroll
    for (int kk = 0; kk < 8; ++kk) {
        half8 a  = *reinterpret_cast<const half8*>(ap + kk * 32);
        half8 b0 = *reinterpret_cast<const half8*>(bp0 + kk * 32);
        half8 b1 = *reinterpret_cast<const half8*>(bp1 + kk * 32);
        acc0 = __builtin_amdgcn_mfma_f32_16x16x32_f16(a, b0, acc0, 0, 0, 0);
        acc1 = __builtin_amdgcn_mfma_f32_16x16x32_f16(a, b1, acc1, 0, 0, 0);
    }
    // C/D: col = lane&15, row = (lane>>4)*4 + reg  [HW-verified]
#pragma unroll
    for (int r = 0; r < 4; ++r) {
        int node = base + wid * 16 + kgrp * 4 + r;
        if (node < n) {
            float d = dinv[node];
            g1h[(size_t)node * 32 + lrow]      = (_Float16)(acc0[r] * d);
            g1h[(size_t)node * 32 + 16 + lrow] = (_Float16)(acc1[r] * d);
        }
    }
}

// accumulate 8 halves (one 16B load) into 8 f32 accumulators
__device__ inline void acc8(float* a, float4 q) {
    const __half2* h = reinterpret_cast<const __half2*>(&q);
#pragma unroll
    for (int i = 0; i < 4; ++i) {
        float2 f = __half22float2(h[i]);
        a[2 * i] += f.x; a[2 * i + 1] += f.y;
    }
}

// padded-CSR gather body: ids via int2/lane + shfl (TA-probe-cheap),
// next iteration's int2 prefetched. Requires (e-s)%8==0 and 8-aligned s.
#define GATHER_BODY(gsrc)                                                         \
    if (s < e) {                                                                  \
        int lb = (tid & 63) & 60;                                                 \
        int2 pr = *reinterpret_cast<const int2*>(&erow[s + 2 * l]);               \
        for (int t = s; t < e; t += 8) {                                          \
            int2 prn = *reinterpret_cast<const int2*>(&erow[t + 8 + 2 * l]);      \
            int r0 = __shfl(pr.x, lb + 0, 64), r1 = __shfl(pr.y, lb + 0, 64);     \
            int r2 = __shfl(pr.x, lb + 1, 64), r3 = __shfl(pr.y, lb + 1, 64);     \
            int r4 = __shfl(pr.x, lb + 2, 64), r5 = __shfl(pr.y, lb + 2, 64);     \
            int r6 = __shfl(pr.x, lb + 3, 64), r7 = __shfl(pr.y, lb + 3, 64);     \
            float4 q0 = gsrc[(size_t)r0 * 4 + l];                                 \
            float4 q1 = gsrc[(size_t)r1 * 4 + l];                                 \
            float4 q2 = gsrc[(size_t)r2 * 4 + l];                                 \
            float4 q3 = gsrc[(size_t)r3 * 4 + l];                                 \
            float4 q4 = gsrc[(size_t)r4 * 4 + l];                                 \
            float4 q5 = gsrc[(size_t)r5 * 4 + l];                                 \
            float4 q6 = gsrc[(size_t)r6 * 4 + l];                                 \
            float4 q7 = gsrc[(size_t)r7 * 4 + l];                                 \
            acc8(a, q0); acc8(b, q1); acc8(a, q2); acc8(b, q3);                   \
            acc8(a, q4); acc8(b, q5); acc8(a, q6); acc8(b, q7);                   \
            pr = prn;                                                             \
        }                                                                         \
    }

// layer-1 aggregate: g2h = fp16( dinv (.) relu(dinv*(sum)+b1) )
__launch_bounds__(256)
__global__ void k_agg1(const float4* __restrict__ g1h4, const int* __restrict__ erow,
                       const int2* __restrict__ ptr2, const float* __restrict__ dinv,
                       const float* __restrict__ b1, int4* __restrict__ g2h4, int n) {
    int tid = threadIdx.x;
    int g = tid >> 2, l = tid & 3;
    int node = blockIdx.x * 64 + g;
    if (node >= n) return;
    int2 pe = ptr2[node];
    int s = pe.x, e = pe.y;
    float a[8] = {0, 0, 0, 0, 0, 0, 0, 0};
    float b[8] = {0, 0, 0, 0, 0, 0, 0, 0};
    acc8(a, g1h4[(size_t)node * 4 + l]);   // self-loop
    GATHER_BODY(g1h4)
    float d = dinv[node];
    float4 bb0 = *reinterpret_cast<const float4*>(&b1[l * 8]);
    float4 bb1 = *reinterpret_cast<const float4*>(&b1[l * 8 + 4]);
    float o[8];
#pragma unroll
    for (int i = 0; i < 8; ++i) {
        float bi = i < 4 ? (&bb0.x)[i] : (&bb1.x)[i - 4];
        float h = fmaf(d, a[i] + b[i], bi);
        o[i] = (h > 0.f ? h : 0.f) * d;
    }
    __half2 h0 = __floats2half2_rn(o[0], o[1]);
    __half2 h1 = __floats2half2_rn(o[2], o[3]);
    __half2 h2 = __floats2half2_rn(o[4], o[5]);
    __half2 h3 = __floats2half2_rn(o[6], o[7]);
    g2h4[(size_t)node * 4 + l] = make_int4(*(int*)&h0, *(int*)&h1, *(int*)&h2, *(int*)&h3);
}

// layer-2 aggregate + W2 projection on MFMA (frh/W2^T fp16 in LDS)
__launch_bounds__(256)
__global__ void k_agg2(const float4* __restrict__ g2h4, const int* __restrict__ erow,
                       const int2* __restrict__ ptr2, const float* __restrict__ dinv,
                       const float* __restrict__ W2, const float* __restrict__ b2,
                       float* __restrict__ out, int n) {
    __shared__ _Float16 frh[64][40];
    __shared__ _Float16 w2h[64][40];   // w2h[col][k] = W2[k][col]
    int tid = threadIdx.x;
    {
        int c = tid >> 2, kb = (tid & 3) * 8;
#pragma unroll
        for (int i = 0; i < 8; ++i)
            w2h[c][kb + i] = (_Float16)W2[(kb + i) * 64 + c];
    }
    int g = tid >> 2, l = tid & 3;
    int node = blockIdx.x * 64 + g;
    float a[8] = {0, 0, 0, 0, 0, 0, 0, 0};
    float b[8] = {0, 0, 0, 0, 0, 0, 0, 0};
    float d = 0.f;
    if (node < n) {
        int2 pe = ptr2[node];
        int s = pe.x, e = pe.y;
        acc8(a, g2h4[(size_t)node * 4 + l]);   // self-loop
        GATHER_BODY(g2h4)
        d = dinv[node];
    }
    {
        _Float16 tmp[8];
#pragma unroll
        for (int i = 0; i < 8; ++i) tmp[i] = (_Float16)(d * (a[i] + b[i]));
        *reinterpret_cast<half8*>(&frh[g][l * 8]) = *reinterpret_cast<half8*>(tmp);
    }
    __syncthreads();
    int w = tid >> 6, lane = tid & 63;
    int lcol = lane & 15, kgrp = lane >> 4;
    half8 afrag = *reinterpret_cast<const half8*>(&frh[w * 16 + lcol][kgrp * 8]);
    half8 bf0 = *reinterpret_cast<const half8*>(&w2h[lcol][kgrp * 8]);
    half8 bf1 = *reinterpret_cast<const half8*>(&w2h[16 + lcol][kgrp * 8]);
    half8 bf2 = *reinterpret_cast<const half8*>(&w2h[32 + lcol][kgrp * 8]);
    half8 bf3 = *reinterpret_cast<const half8*>(&w2h[48 + lcol][kgrp * 8]);
    f32x4 c0 = {0.f, 0.f, 0.f, 0.f}, c1 = c0, c2 = c0, c3 = c0;
    c0 = __builtin_amdgcn_mfma_f32_16x16x32_f16(afrag, bf0, c0, 0, 0, 0);
    c1 = __builtin_amdgcn_mfma_f32_16x16x32_f16(afrag, bf1, c1, 0, 0, 0);
    c2 = __builtin_amdgcn_mfma_f32_16x16x32_f16(afrag, bf2, c2, 0, 0, 0);
    c3 = __builtin_amdgcn_mfma_f32_16x16x32_f16(afrag, bf3, c3, 0, 0, 0);
    float bi0 = b2[lcol], bi1 = b2[16 + lcol], bi2 = b2[32 + lcol], bi3 = b2[48 + lcol];
#pragma unroll
    for (int r = 0; r < 4; ++r) {
        int node2 = blockIdx.x * 64 + w * 16 + kgrp * 4 + r;
        if (node2 < n) {
            float* op = &out[(size_t)node2 * 64];
            op[lcol]      = c0[r] + bi0;
            op[16 + lcol] = c1[r] + bi1;
            op[32 + lcol] = c2[r] + bi2;
            op[48 + lcol] = c3[r] + bi3;
        }
    }
}

extern "C" void kernel_launch(void* const* d_in, const int* in_sizes, int n_in,
                              void* d_out, int out_size, void* d_ws, size_t ws_size,
                              hipStream_t stream) {
    const float* x  = (const float*)d_in[0];
    const int*   ei = (const int*)d_in[1];
    const float* W1 = (const float*)d_in[2];
    const float* b1 = (const float*)d_in[3];
    const float* W2 = (const float*)d_in[4];
    const float* b2 = (const float*)d_in[5];
    float* out = (float*)d_out;

    const int N = in_sizes[0] / 256;
    const int E = in_sizes[1] / 2;
    const int* rows = ei;        // edge_index[0] (source)
    const int* cols = ei + E;    // edge_index[1] (dest)
    const int NB1 = (N + S1 - 1) >> SHIFT1;   // 391 coarse buckets

    // ws layout (4B units):
    // buf0 = pk[E] aliased with g1h[(N+1)*32 halves] (pk dead after fine)
    // | erow[E + NB1*BSLACK + 64] | g2h[(N+1)*32 halves] | dinv[N] | ptr2[N] (int2)
    // | bptr1 | bcnt1 | bfill1
    size_t g1w = (size_t)(N + 1) * 16;             // g table words
    size_t sz0 = (size_t)E > g1w ? (size_t)E : g1w;
    size_t szE = (size_t)E + (size_t)NB1 * BSLACK + 64;
    unsigned* pk   = (unsigned*)d_ws;
    _Float16* g1h  = (_Float16*)d_ws;
    int*      erow = (int*)d_ws + sz0;
    _Float16* g2h  = (_Float16*)(erow + szE);
    float*    dinv = (float*)((int*)(erow + szE) + g1w);
    int2*     ptr2 = (int2*)(dinv + N);
    int*      bptr1 = (int*)(ptr2 + N);
    int*      bcnt1 = bptr1 + (NB1 + 1);
    int*      bfill1 = bcnt1 + NB1;

    const int B = 256;
    const int e4 = E / 4, etail = E - e4 * 4;
    const int SCB = 256;
    const int chunk = (E + SCB - 1) / SCB;
    const int nblk64 = (N + 63) / 64;

    k_zero<<<(NB1 + B - 1) / B, B, 0, stream>>>(bcnt1, NB1);
    k_hist1<<<256, B, 0, stream>>>((const int4*)cols, bcnt1, e4, etail, cols, NB1);
    k_scan1<<<1, 512, 0, stream>>>(bcnt1, bptr1, bfill1, NB1, E);
    k_scatter1<<<SCB, 1024, 0, stream>>>(rows, cols, bfill1, pk, E, NB1, chunk);
    k_fine256<<<NB1, 512, 0, stream>>>(pk, bptr1, erow, ptr2, dinv, N, NB1);
    k_zrow<<<1, 64, 0, stream>>>(g1h, g2h, N);
    k_xw_mfma<<<nblk64, B, 0, stream>>>((const float4*)x, (const float4*)W1, dinv, g1h, N);
    k_agg1<<<nblk64, B, 0, stream>>>((const float4*)g1h, erow, ptr2, dinv, b1, (int4*)g2h, N);
    k_agg2<<<nblk64, B, 0, stream>>>((const float4*)g2h, erow, ptr2, dinv, W2, b2, out, N);
}